// Round 5
// baseline (215.803 us; speedup 1.0000x reference)
//
#include <hip/hip_runtime.h>

#define LAMBDA_COORD 5.0f
#define LAMBDA_NOOBJ 0.5f
#define WH_EPS 1e-6f
#define IOU_EPS 1e-6f

// Round-4: NAMED-REGISTER payload — no arrays, no pointer casts, no scratch.
//
// Round-3 post-mortem: WRITE_SIZE ~60 MB (kernel writes 6 KB) + VGPR_Count=64
// proved the float4 tb[15]/pb[15] buffers were demoted to SCRATCH (the
// (const float*)tb cast + tf+30 reindexing defeated SROA). Every thread
// round-tripped 240 B through scratch: ~150 MB of phantom HBM/L2 traffic,
// and the load pipeline was serialized through stack stores.
//
// Fix: 30 named float4 variables, cell losses computed from explicit
// components. No memory object exists -> the payload MUST live in VGPRs
// (~150), loads are 30 independent global_load_dwordx4 issued before use.
// 401,408 pairs = 1568 blocks x 256 threads exactly; one pair per thread.

constexpr int THREADS = 256;

__device__ __forceinline__ float iou_yolo(float a0, float a1, float a2, float a3,
                                          float b0, float b1, float b2, float b3) {
    float ax1 = a0 - a2 * 0.5f, ay1 = a1 - a3 * 0.5f;
    float ax2 = a0 + a2 * 0.5f, ay2 = a1 + a3 * 0.5f;
    float bx1 = b0 - b2 * 0.5f, by1 = b1 - b3 * 0.5f;
    float bx2 = b0 + b2 * 0.5f, by2 = b1 + b3 * 0.5f;
    float iw = fmaxf(fminf(ax2, bx2) - fmaxf(ax1, bx1), 0.0f);
    float ih = fmaxf(fminf(ay2, by2) - fmaxf(ay1, by1), 0.0f);
    float inter = iw * ih;
    float area_a = fabsf((ax2 - ax1) * (ay2 - ay1));
    float area_b = fabsf((bx2 - bx1) * (by2 - by1));
    return inter / (area_a + area_b - inter + IOU_EPS);
}

// One cell's loss from explicit scalars.
// b*: true box, t4: true conf; q*: pred box1 (+qc conf1); r*: pred box2 (+rc conf2);
// cls: precomputed sum of squared class diffs.
__device__ __forceinline__ float yolo_cell(
    float b0, float b1, float b2, float b3, float t4,
    float q0, float q1, float q2, float q3, float qc,
    float r0, float r1, float r2, float r3, float rc,
    float cls) {
    float iou1 = iou_yolo(b0, b1, b2, b3, q0, q1, q2, q3);
    float iou2 = iou_yolo(b0, b1, b2, b3, r0, r1, r2, r3);
    bool use1 = iou1 > iou2;

    float bh0 = use1 ? q0 : r0;
    float bh1 = use1 ? q1 : r1;
    float bh2 = use1 ? q2 : r2;
    float bh3 = use1 ? q3 : r3;
    float conf_c = use1 ? qc : rc;
    float conf_o = use1 ? rc : qc;

    float dx = b0 - bh0, dy = b1 - bh1;
    float xy = LAMBDA_COORD * (dx * dx + dy * dy);

    float sw = sqrtf(b2) - sqrtf(fabsf(bh2 + WH_EPS));
    float sh = sqrtf(b3) - sqrtf(fabsf(bh3 + WH_EPS));
    float wh = LAMBDA_COORD * (sw * sw + sh * sh);

    float dc = t4 - conf_c;
    float obj_conf = dc * dc;
    float noobj_in_obj = LAMBDA_NOOBJ * conf_o * conf_o;

    float obj_terms = xy + wh + obj_conf + noobj_in_obj + cls;

    float d4 = t4 - qc, d9 = t4 - rc;
    float noobj_terms = LAMBDA_NOOBJ * (d4 * d4 + d9 * d9);

    return (t4 == 1.0f) ? obj_terms : noobj_terms;
}

__device__ __forceinline__ float sq4(float4 a, float4 b) {
    float dx = a.x - b.x, dy = a.y - b.y, dz = a.z - b.z, dw = a.w - b.w;
    return dx * dx + dy * dy + dz * dz + dw * dw;
}
__device__ __forceinline__ float sq2lo(float4 a, float4 b) {  // x,y only
    float dx = a.x - b.x, dy = a.y - b.y;
    return dx * dx + dy * dy;
}
__device__ __forceinline__ float sq2hi(float4 a, float4 b) {  // z,w only
    float dz = a.z - b.z, dw = a.w - b.w;
    return dz * dz + dw * dw;
}

__global__ __launch_bounds__(THREADS, 2) void yolo_loss_main(
    const float4* __restrict__ tv, const float4* __restrict__ pv,
    float* __restrict__ ws, int npairs) {
    const int pair = blockIdx.x * THREADS + threadIdx.x;

    float v = 0.0f;
    if (pair < npairs) {
        const float4* tg = tv + (size_t)pair * 15;
        const float4* pg = pv + (size_t)pair * 15;

        // 30 independent 16-B loads into NAMED registers.
        float4 ta0 = tg[0],  ta1 = tg[1],  ta2 = tg[2],  ta3 = tg[3],  ta4 = tg[4];
        float4 ta5 = tg[5],  ta6 = tg[6],  ta7 = tg[7],  ta8 = tg[8],  ta9 = tg[9];
        float4 ta10 = tg[10], ta11 = tg[11], ta12 = tg[12], ta13 = tg[13], ta14 = tg[14];
        float4 pa0 = pg[0],  pa1 = pg[1],  pa2 = pg[2],  pa3 = pg[3],  pa4 = pg[4];
        float4 pa5 = pg[5],  pa6 = pg[6],  pa7 = pg[7],  pa8 = pg[8],  pa9 = pg[9];
        float4 pa10 = pg[10], pa11 = pg[11], pa12 = pg[12], pa13 = pg[13], pa14 = pg[14];
        (void)ta9;  // true[35..39] unused by the loss (truth's 2nd-box slot)

        // Cell A = pair floats [0,30):
        //   t box = ta0.xyzw, conf = ta1.x
        //   p box1 = pa0.xyzw, conf1 = pa1.x; box2 = pa1.y,pa1.z,pa1.w,pa2.x, conf2 = pa2.y
        //   cls = floats 10..29 -> ta2.zw, ta3..ta6, ta7.xy
        float clsA = sq2hi(ta2, pa2) + sq4(ta3, pa3) + sq4(ta4, pa4)
                   + sq4(ta5, pa5) + sq4(ta6, pa6) + sq2lo(ta7, pa7);
        float lossA = yolo_cell(ta0.x, ta0.y, ta0.z, ta0.w, ta1.x,
                                pa0.x, pa0.y, pa0.z, pa0.w, pa1.x,
                                pa1.y, pa1.z, pa1.w, pa2.x, pa2.y,
                                clsA);

        // Cell B = pair floats [30,60):
        //   t box = ta7.zw, ta8.xy, conf = ta8.z
        //   p box1 = pa7.zw, pa8.xy, conf1 = pa8.z; box2 = pa8.w, pa9.xyz, conf2 = pa9.w
        //   cls = floats 40..59 -> ta10..ta14 (full float4s)
        float clsB = sq4(ta10, pa10) + sq4(ta11, pa11) + sq4(ta12, pa12)
                   + sq4(ta13, pa13) + sq4(ta14, pa14);
        float lossB = yolo_cell(ta7.z, ta7.w, ta8.x, ta8.y, ta8.z,
                                pa7.z, pa7.w, pa8.x, pa8.y, pa8.z,
                                pa8.w, pa9.x, pa9.y, pa9.z, pa9.w,
                                clsB);

        v = lossA + lossB;
    }

    // wave64 reduction
#pragma unroll
    for (int off = 32; off > 0; off >>= 1)
        v += __shfl_down(v, off, 64);

    // block reduction -> one plain store per block (no same-address atomics)
    __shared__ float part[THREADS / 64];
    if ((threadIdx.x & 63) == 0) part[threadIdx.x >> 6] = v;
    __syncthreads();
    if (threadIdx.x == 0) {
        float s = 0.0f;
#pragma unroll
        for (int w = 0; w < THREADS / 64; ++w) s += part[w];
        ws[blockIdx.x] = s;
    }
}

__global__ __launch_bounds__(256) void yolo_loss_finish(
    const float* __restrict__ ws, float* __restrict__ out,
    int nblocks, float inv_batch) {
    float v = 0.0f;
    for (int i = threadIdx.x; i < nblocks; i += 256) v += ws[i];
#pragma unroll
    for (int off = 32; off > 0; off >>= 1)
        v += __shfl_down(v, off, 64);
    __shared__ float part[4];
    if ((threadIdx.x & 63) == 0) part[threadIdx.x >> 6] = v;
    __syncthreads();
    if (threadIdx.x == 0)
        out[0] = (part[0] + part[1] + part[2] + part[3]) * inv_batch;
}

extern "C" void kernel_launch(void* const* d_in, const int* in_sizes, int n_in,
                              void* d_out, int out_size, void* d_ws, size_t ws_size,
                              hipStream_t stream) {
    const float* t = (const float*)d_in[0];  // y_trues
    const float* p = (const float*)d_in[1];  // y_preds
    float* out = (float*)d_out;
    float* ws = (float*)d_ws;

    const int total = in_sizes[0];            // 24,084,480 floats
    const int cells = total / 30;             // 802,816
    const int npairs = cells / 2;             // 401,408
    const int batch = cells / 49;             // 16,384
    const float inv_batch = 1.0f / (float)batch;

    // 1 pair per thread: 1568 blocks x 256 threads = 401,408 exactly.
    const int blocks = (npairs + THREADS - 1) / THREADS;

    yolo_loss_main<<<blocks, THREADS, 0, stream>>>(
        (const float4*)t, (const float4*)p, ws, npairs);
    yolo_loss_finish<<<1, 256, 0, stream>>>(ws, out, blocks, inv_batch);
}

// Round 6
// 205.840 us; speedup vs baseline: 1.0484x; 1.0484x over previous
//
#include <hip/hip_runtime.h>

#define LAMBDA_COORD 5.0f
#define LAMBDA_NOOBJ 0.5f
#define WH_EPS 1e-6f
#define IOU_EPS 1e-6f

// Round-6: coalesced global->LDS DMA bursts + high in-flight bytes per CU.
//
// Round-5 post-mortem: named registers still gave VGPR_Count=60 — the
// scheduler sank loads next to uses (pressure-min objective), so each wave
// had ~2-3 load epochs; AND the per-lane stride-240 pattern makes every
// lane of a dwordx4 touch a different 128-B line (~64 TA lookups/instr vs 8
// coalesced). Per-CU delivery measured 9.4 B/cy (~6 lines in flight). Both
// problems disappear with lane-contiguous global_load_lds DMA:
//  - no destination VGPRs -> compiler cannot cluster/serialize the loads;
//  - lane i reads chunk base+i*16 -> perfectly coalesced;
//  - each wave posts 15 KB in one burst; 2 blocks/CU x 8 waves -> ~120 KB
//    in flight per CU during the single vmcnt(0)+barrier.
// Block = 256 threads stages 256 cells (t:30,720 B + p:30,720 B = 61,440 B
// LDS), computes 1 cell/thread from LDS (120-B lane stride: round-0 counters
// showed negligible bank conflicts for this read pattern). 3136 one-shot
// blocks = 12 generations/CU overlap each other's DMA latency.

constexpr int THREADS = 256;
// per tile: 256 cells * 30 floats = 7680 floats = 1920 float4 per array
constexpr int TILE_VEC4 = 1920;

__device__ __forceinline__ float iou_yolo(float a0, float a1, float a2, float a3,
                                          float b0, float b1, float b2, float b3) {
    float ax1 = a0 - a2 * 0.5f, ay1 = a1 - a3 * 0.5f;
    float ax2 = a0 + a2 * 0.5f, ay2 = a1 + a3 * 0.5f;
    float bx1 = b0 - b2 * 0.5f, by1 = b1 - b3 * 0.5f;
    float bx2 = b0 + b2 * 0.5f, by2 = b1 + b3 * 0.5f;
    float iw = fmaxf(fminf(ax2, bx2) - fmaxf(ax1, bx1), 0.0f);
    float ih = fmaxf(fminf(ay2, by2) - fmaxf(ay1, by1), 0.0f);
    float inter = iw * ih;
    float area_a = fabsf((ax2 - ax1) * (ay2 - ay1));
    float area_b = fabsf((bx2 - bx1) * (by2 - by1));
    return inter / (area_a + area_b - inter + IOU_EPS);
}

// Full loss for one cell; t/p point at 30 consecutive floats in LDS.
// (Identical to the round-0 kernel that verified bit-exact; compiles to
// ds_read + VALU with constant indices, ~negligible bank conflicts.)
__device__ __forceinline__ float cell_loss(const float* t, const float* p) {
    const float b0 = t[0], b1 = t[1], b2 = t[2], b3 = t[3], t4 = t[4];

    float iou1 = iou_yolo(b0, b1, b2, b3, p[0], p[1], p[2], p[3]);
    float iou2 = iou_yolo(b0, b1, b2, b3, p[5], p[6], p[7], p[8]);
    bool use1 = iou1 > iou2;

    float bh0 = use1 ? p[0] : p[5];
    float bh1 = use1 ? p[1] : p[6];
    float bh2 = use1 ? p[2] : p[7];
    float bh3 = use1 ? p[3] : p[8];
    float conf_c = use1 ? p[4] : p[9];
    float conf_o = use1 ? p[9] : p[4];

    float dx = b0 - bh0, dy = b1 - bh1;
    float xy = LAMBDA_COORD * (dx * dx + dy * dy);

    float sw = sqrtf(b2) - sqrtf(fabsf(bh2 + WH_EPS));
    float sh = sqrtf(b3) - sqrtf(fabsf(bh3 + WH_EPS));
    float wh = LAMBDA_COORD * (sw * sw + sh * sh);

    float dc = t4 - conf_c;
    float obj_conf = dc * dc;
    float noobj_in_obj = LAMBDA_NOOBJ * conf_o * conf_o;

    float cls = 0.0f;
#pragma unroll
    for (int k = 10; k < 30; ++k) {
        float d = t[k] - p[k];
        cls += d * d;
    }

    float obj_terms = xy + wh + obj_conf + noobj_in_obj + cls;

    float d4 = t4 - p[4], d9 = t4 - p[9];
    float noobj_terms = LAMBDA_NOOBJ * (d4 * d4 + d9 * d9);

    return (t4 == 1.0f) ? obj_terms : noobj_terms;
}

// 16-B global->LDS DMA: wave-uniform LDS base, per-lane global address.
__device__ __forceinline__ void stage16(const float4* g_lane, float4* l_wave) {
    __builtin_amdgcn_global_load_lds(
        (const __attribute__((address_space(1))) void*)g_lane,
        (__attribute__((address_space(3))) void*)l_wave,
        16, 0, 0);
}

__global__ __launch_bounds__(THREADS, 2) void yolo_loss_main(
    const float4* __restrict__ tv, const float4* __restrict__ pv,
    float* __restrict__ ws) {
    // [0,1920) = t tile, [1920,3840) = p tile; 61,440 B -> 2 blocks/CU.
    __shared__ float4 sbuf[2 * TILE_VEC4];
    __shared__ float part[THREADS / 64];

    const int lane = threadIdx.x & 63;
    const int wid  = threadIdx.x >> 6;
    const size_t base = (size_t)blockIdx.x * TILE_VEC4;  // per-array chunk base

    // Stage 3840 chunks with 15 rounds of 256 lane-contiguous DMAs.
    // Round j, wave w covers chunks [j*256 + w*64, +64): each wave's 64
    // chunks lie entirely within one array (1920 is a multiple of 64), so
    // the global addresses are lane-contiguous and the LDS base is
    // wave-uniform — exactly the global_load_lds contract.
#pragma unroll
    for (int j = 0; j < 15; ++j) {
        const int idx = j * THREADS + wid * 64;        // wave-uniform
        const int myidx = idx + lane;                   // per-lane chunk
        const float4* src = (myidx < TILE_VEC4)
                          ? (tv + base + myidx)
                          : (pv + base + (myidx - TILE_VEC4));
        stage16(src, sbuf + idx);
    }

    __syncthreads();   // drains vmcnt(0): all DMA data visible in LDS

    const float* st = (const float*)sbuf;                // cell c at st + c*30
    const float* sp = (const float*)(sbuf + TILE_VEC4);  // cell c at sp + c*30
    float v = cell_loss(st + threadIdx.x * 30, sp + threadIdx.x * 30);

    // wave64 reduction
#pragma unroll
    for (int off = 32; off > 0; off >>= 1)
        v += __shfl_down(v, off, 64);

    // block reduction -> one plain store per block (no same-address atomics)
    if (lane == 0) part[wid] = v;
    __syncthreads();
    if (threadIdx.x == 0) {
        float s = 0.0f;
#pragma unroll
        for (int w = 0; w < THREADS / 64; ++w) s += part[w];
        ws[blockIdx.x] = s;
    }
}

__global__ __launch_bounds__(256) void yolo_loss_finish(
    const float* __restrict__ ws, float* __restrict__ out,
    int nblocks, float inv_batch) {
    float v = 0.0f;
    for (int i = threadIdx.x; i < nblocks; i += 256) v += ws[i];
#pragma unroll
    for (int off = 32; off > 0; off >>= 1)
        v += __shfl_down(v, off, 64);
    __shared__ float part[4];
    if ((threadIdx.x & 63) == 0) part[threadIdx.x >> 6] = v;
    __syncthreads();
    if (threadIdx.x == 0)
        out[0] = (part[0] + part[1] + part[2] + part[3]) * inv_batch;
}

extern "C" void kernel_launch(void* const* d_in, const int* in_sizes, int n_in,
                              void* d_out, int out_size, void* d_ws, size_t ws_size,
                              hipStream_t stream) {
    const float* t = (const float*)d_in[0];  // y_trues
    const float* p = (const float*)d_in[1];  // y_preds
    float* out = (float*)d_out;
    float* ws = (float*)d_ws;

    const int total = in_sizes[0];            // 24,084,480 floats
    const int cells = total / 30;             // 802,816
    const int batch = cells / 49;             // 16,384
    const float inv_batch = 1.0f / (float)batch;

    // 256 cells per block: 3136 blocks x 256 threads = 802,816 exactly.
    const int blocks = cells / THREADS;       // 3136, exact

    yolo_loss_main<<<blocks, THREADS, 0, stream>>>(
        (const float4*)t, (const float4*)p, ws);
    yolo_loss_finish<<<1, 256, 0, stream>>>(ws, out, blocks, inv_batch);
}